// Round 8
// baseline (7277.931 us; speedup 1.0000x reference)
//
#include <hip/hip_runtime.h>
#include <hip/hip_bf16.h>
#include <hip/hip_fp16.h>

// Problem sizes
#define NB 32
#define NT 256
#define NH 256
#define NV 32000
#define NL2 512     // fixed KV length = 2T
#define NTP1 257    // T+1

typedef unsigned int u32x4 __attribute__((ext_vector_type(4)));
typedef unsigned int u32x2 __attribute__((ext_vector_type(2)));
typedef short s16x8 __attribute__((ext_vector_type(8)));
typedef float f32x4 __attribute__((ext_vector_type(4)));
typedef _Float16 half2v __attribute__((ext_vector_type(2)));

#define AGENT __HIP_MEMORY_SCOPE_AGENT
__device__ __forceinline__ float aload(const float* p) {
  return __hip_atomic_load((float*)p, __ATOMIC_RELAXED, AGENT);
}
__device__ __forceinline__ void astore(float* p, float v) {
  __hip_atomic_store(p, v, __ATOMIC_RELAXED, AGENT);
}

__device__ __forceinline__ float dot2f(half2v a, half2v b, float c) {
#if __has_builtin(__builtin_amdgcn_fdot2)
  return __builtin_amdgcn_fdot2(a, b, c, false);
#else
  return c + (float)a[0] * (float)b[0] + (float)a[1] * (float)b[1];
#endif
}
__device__ __forceinline__ half2v h2(unsigned int u) { return __builtin_bit_cast(half2v, u); }

// 16-element f16 dot (one 32B chunk), fp32 acc
__device__ __forceinline__ float dot16h(const _Float16* __restrict__ w,
                                        const _Float16* __restrict__ x) {
  u32x4 a0 = *(const u32x4*)w;
  u32x4 a1 = *(const u32x4*)(w + 8);
  u32x4 b0 = *(const u32x4*)x;
  u32x4 b1 = *(const u32x4*)(x + 8);
  float acc = 0.f;
  acc = dot2f(h2(a0.x), h2(b0.x), acc);
  acc = dot2f(h2(a0.y), h2(b0.y), acc);
  acc = dot2f(h2(a0.z), h2(b0.z), acc);
  acc = dot2f(h2(a0.w), h2(b0.w), acc);
  acc = dot2f(h2(a1.x), h2(b1.x), acc);
  acc = dot2f(h2(a1.y), h2(b1.y), acc);
  acc = dot2f(h2(a1.z), h2(b1.z), acc);
  acc = dot2f(h2(a1.w), h2(b1.w), acc);
  return acc;
}

__device__ __forceinline__ float fast_tanh(float x) {
  x = fminf(15.f, fmaxf(-15.f, x));
  float e = __expf(2.f * x);
  return 1.f - __fdividef(2.f, e + 1.f);
}
__device__ __forceinline__ float fast_sigmoid(float x) {
  x = fminf(30.f, fmaxf(-30.f, x));
  float e = __expf(-x);
  return __fdividef(1.f, 1.f + e);
}
__device__ __forceinline__ unsigned short f2bf(float f) {  // RNE fp32->bf16
  unsigned int u = __builtin_bit_cast(unsigned int, f);
  return (unsigned short)((u + 0x7FFFu + ((u >> 16) & 1u)) >> 16);
}

// split arrive/wait fence-free barrier (protocol proven in R6/R7):
//  arrive: syncthreads (drains this WG's stores) + release fetch_add
//  wait:   relaxed agent spin + compiler barrier + syncthreads
__device__ __forceinline__ void bar_arrive(int* __restrict__ ctr) {
  __syncthreads();
  if (threadIdx.x == 0)
    __hip_atomic_fetch_add(ctr, 1, __ATOMIC_RELEASE, AGENT);
}
__device__ __forceinline__ void bar_wait(int* __restrict__ ctr, int target) {
  if (threadIdx.x == 0) {
    while (__hip_atomic_load(ctr, __ATOMIC_RELAXED, AGENT) < target)
      __builtin_amdgcn_s_sleep(1);
    asm volatile("" ::: "memory");
  }
  __syncthreads();
}

// ---------------- setup kernels ----------------

__global__ void conv_f16_kernel(const float* __restrict__ s, _Float16* __restrict__ d, int n) {
  int i = blockIdx.x * 256 + threadIdx.x;
  if (i < n) d[i] = (_Float16)s[i];
}

__global__ void conv_bf16_kernel(const float* __restrict__ s, unsigned short* __restrict__ d, int n) {
  int i = blockIdx.x * 256 + threadIdx.x;
  if (i < n) d[i] = f2bf(s[i]);
}

// pack-transpose: out[k2][r] = f16pair(w[r][2k2], w[r][2k2+1]); coalesced writes
__global__ void packT_kernel(const float* __restrict__ w, unsigned int* __restrict__ out,
                             int R, int K) {
  int gid = blockIdx.x * 256 + threadIdx.x;
  int K2 = K >> 1;
  if (gid >= R * K2) return;
  int k2 = gid / R, r = gid - k2 * R;
  unsigned short ua = __builtin_bit_cast(unsigned short, (_Float16)w[(size_t)r * K + 2 * k2]);
  unsigned short ub = __builtin_bit_cast(unsigned short, (_Float16)w[(size_t)r * K + 2 * k2 + 1]);
  out[(size_t)k2 * R + r] = (unsigned int)ua | ((unsigned int)ub << 16);
}

// enc_proj_w (256,512) -> wT (512,256)
__global__ void transpose_kernel(const float* __restrict__ w, float* __restrict__ wT) {
  int i = blockIdx.x * 256 + threadIdx.x;
  if (i < 256 * 512) { int h = i >> 9, dd = i & 511; wT[dd * 256 + h] = w[i]; }
}

// proj[b,s,h] = enc_proj_b[h] + sum_d enc[s,b,d]*W[h,d]; write kvL[b][l=s][h] (f16)
__global__ __launch_bounds__(256) void proj_kernel(const float* __restrict__ enc,
                                                   const float* __restrict__ wT,
                                                   const float* __restrict__ pb,
                                                   _Float16* __restrict__ kvL) {
  int gid = blockIdx.x * 256 + threadIdx.x;
  int h4 = gid & 63;
  int bs = gid >> 6;                 // = s*32 + b (matches enc layout)
  if (bs >= NTP1 * NB) return;
  int s = bs >> 5, b = bs & 31;
  const float* er = enc + (size_t)bs * 512;
  float a0 = 0.f, a1 = 0.f, a2 = 0.f, a3 = 0.f;
  for (int d = 0; d < 512; d += 4) {
    f32x4 e4 = *(const f32x4*)(er + d);
    f32x4 w0 = *(const f32x4*)(wT + (size_t)(d + 0) * 256 + h4 * 4);
    f32x4 w1 = *(const f32x4*)(wT + (size_t)(d + 1) * 256 + h4 * 4);
    f32x4 w2 = *(const f32x4*)(wT + (size_t)(d + 2) * 256 + h4 * 4);
    f32x4 w3 = *(const f32x4*)(wT + (size_t)(d + 3) * 256 + h4 * 4);
    a0 = fmaf(e4.x, w0.x, a0); a1 = fmaf(e4.x, w0.y, a1); a2 = fmaf(e4.x, w0.z, a2); a3 = fmaf(e4.x, w0.w, a3);
    a0 = fmaf(e4.y, w1.x, a0); a1 = fmaf(e4.y, w1.y, a1); a2 = fmaf(e4.y, w1.z, a2); a3 = fmaf(e4.y, w1.w, a3);
    a0 = fmaf(e4.z, w2.x, a0); a1 = fmaf(e4.z, w2.y, a1); a2 = fmaf(e4.z, w2.z, a2); a3 = fmaf(e4.z, w2.w, a3);
    a0 = fmaf(e4.w, w3.x, a0); a1 = fmaf(e4.w, w3.y, a1); a2 = fmaf(e4.w, w3.z, a2); a3 = fmaf(e4.w, w3.w, a3);
  }
  int h = h4 * 4;
  a0 += pb[h + 0]; a1 += pb[h + 1]; a2 += pb[h + 2]; a3 += pb[h + 3];
  _Float16* dst = kvL + ((size_t)b * 512 + s) * 256 + h;
  dst[0] = (_Float16)a0; dst[1] = (_Float16)a1;
  dst[2] = (_Float16)a2; dst[3] = (_Float16)a3;
}

// kprojL[b][l][g] = sum_h kvL[b][l][h] * wk[g][h], for l < 257 (f16 out)
__global__ __launch_bounds__(256) void kproj0_kernel(const _Float16* __restrict__ kvL,
                                                     const float* __restrict__ wk,
                                                     _Float16* __restrict__ kprojL) {
  int b = blockIdx.x >> 3, gq = blockIdx.x & 7;
  __shared__ float wks[32][256];
  __shared__ float pk[32][8];
  int tid = threadIdx.x;
  for (int i = tid; i < 32 * 256; i += 256) {
    int g = i >> 8, h = i & 255;
    wks[g][h] = wk[(size_t)(gq * 32 + g) * 256 + h];
  }
  __syncthreads();
  {
    int l = tid;   // l in [0,256)
    float acc[32];
#pragma unroll
    for (int g = 0; g < 32; ++g) acc[g] = 0.f;
    for (int h = 0; h < 256; ++h) {
      float kvv = (float)kvL[((size_t)b * 512 + l) * 256 + h];
#pragma unroll
      for (int g = 0; g < 32; ++g) acc[g] = fmaf(kvv, wks[g][h], acc[g]);
    }
    for (int g = 0; g < 32; ++g)
      kprojL[((size_t)b * NL2 + l) * NH + gq * 32 + g] = (_Float16)acc[g];
  }
  // l == 256 handled cooperatively
  {
    int g = tid >> 3, hc = tid & 7;
    float acc = 0.f;
    for (int h = hc * 32; h < hc * 32 + 32; ++h)
      acc += (float)kvL[((size_t)b * 512 + 256) * 256 + h] * wks[g][h];
    pk[g][hc] = acc;
    __syncthreads();
    if (tid < 32) {
      float sv = 0.f;
      for (int c = 0; c < 8; ++c) sv += pk[tid][c];
      kprojL[((size_t)b * NL2 + 256) * NH + gq * 32 + tid] = (_Float16)sv;
    }
  }
}

// ---------------- cooperative scan: 8 WGs/batch, 3 split barriers/step, hoisted gh ----
// blockIdx: b = blk & 31, s = blk >> 5. Slices: g/h-slice [32s,32s+32), k2-slice [16s,16s+16).
// vec layout per (buf,b,sp): [0..768) gi partials, [768..1536) gh partials. buf = t&1.

__global__ __launch_bounds__(512) void scan_kernel(
    const int* __restrict__ x, const float* __restrict__ efs, const float* __restrict__ emb,
    const float* __restrict__ wv,
    const float* __restrict__ bih0, const float* __restrict__ bhh0,
    const float* __restrict__ bih1, const float* __restrict__ bhh1,
    const _Float16* __restrict__ wq16, const _Float16* __restrict__ wk16,
    const unsigned int* __restrict__ wih0T, const unsigned int* __restrict__ whh0T,
    const unsigned int* __restrict__ wih1T, const unsigned int* __restrict__ whh1T,
    const unsigned int* __restrict__ kvL_u, const unsigned int* __restrict__ kprojL_u,
    float* __restrict__ spart, float* __restrict__ vec0, float* __restrict__ vec1,
    int* __restrict__ bars,
    unsigned short* __restrict__ outs_bf, float* __restrict__ attn_out) {
  __shared__ __align__(16) unsigned int kp_u[512 * 17];  // kproj slice: f16[512][34], 16 u32 used
  __shared__ __align__(16) unsigned int kv_u[512 * 19];  // kv slice: pairs [512][19], 16 used
  __shared__ __align__(16) float att[512], gsum[1024];
  __shared__ __align__(16) float h0s[256], h1s[256];
  __shared__ __align__(16) float scr[544], scr2[32 * 35];
  __shared__ __align__(16) float qs[32], wvs[32], red[16];
  __shared__ __align__(16) _Float16 h0h[256], h1h[256], xinh[64];

  int tid = threadIdx.x;
  int b = blockIdx.x & 31;
  int s = blockIdx.x >> 5;
  int* bar = bars + b * 32;

  // replicated state init
  if (tid < 256) {
    float h0v = efs[(size_t)(0 * NB + b) * NH + tid] + efs[(size_t)(1 * NB + b) * NH + tid];
    float h1v = efs[(size_t)(2 * NB + b) * NH + tid] + efs[(size_t)(3 * NB + b) * NH + tid];
    h0s[tid] = h0v; h0h[tid] = (_Float16)h0v;
    h1s[tid] = h1v; h1h[tid] = (_Float16)h1v;
  }
  if (tid < 32) wvs[tid] = wv[32 * s + tid];
  // emb slice for t=0
  if (tid >= 480) {
    int j = tid - 480;
    int tok = x[b * NT + 0];
    xinh[32 + j] = (_Float16)emb[(size_t)tok * 256 + 32 * s + j];
  }
  // init private kp/kv LDS slices (cols = local u32 pairs of the 32-wide slice)
  for (int idx = tid; idx < 257 * 16; idx += 512) {
    int l = idx >> 4, c = idx & 15;
    kp_u[l * 17 + c] = kprojL_u[((size_t)b * 512 + l) * 128 + 16 * s + c];
    kv_u[l * 19 + c] = kvL_u[((size_t)b * 512 + l) * 128 + 16 * s + c];
  }
  for (int idx = tid; idx < 255 * 16; idx += 512) {
    int l = 257 + (idx >> 4), c = idx & 15;
    kp_u[l * 17 + c] = 0u;
    kv_u[l * 19 + c] = 0u;
  }
  __syncthreads();

  for (int t = 0; t < NT; ++t) {
    int Lt = NTP1 + t;
    int tgt = 8 * (t + 1);
    int buf = t & 1;
    const size_t vbase = ((size_t)(buf * NB + b)) * 8;
    // -- P1: q slice (local; h1 replicated)
    {
      int row = tid & 31, ch = tid >> 5;
      scr[ch * 33 + row] = dot16h(wq16 + (size_t)(32 * s + row) * 256 + ch * 16, h1h + ch * 16);
    }
    __syncthreads();
    if (tid < 32) {
      float a = 0.f;
#pragma unroll
      for (int c = 0; c < 16; ++c) a += scr[c * 33 + tid];
      qs[tid] = a;
    }
    __syncthreads();
    // -- P2: score partials over local g-chunk, l = tid
    {
      float acc = 0.f;
      if (tid < Lt) {
        const unsigned int* kr = kp_u + tid * 17;
#pragma unroll 4
        for (int g2 = 0; g2 < 16; ++g2) {
          half2v kp2 = h2(kr[g2]);
          acc = fmaf(wvs[2 * g2 + 0], fast_tanh((float)kp2[0] + qs[2 * g2 + 0]), acc);
          acc = fmaf(wvs[2 * g2 + 1], fast_tanh((float)kp2[1] + qs[2 * g2 + 1]), acc);
        }
      }
      astore(spart + ((size_t)(b * 8 + s)) * 512 + tid, acc);
    }
    bar_arrive(bar + 0);           // E1 arrive: score partials
    // == A-gap: hoisted gh0 = whh0 @ h0_old, gh1 = whh1 @ h1_old (independent) ==
    {
      const unsigned int* h0u = (const unsigned int*)h0h;
      const unsigned int* h1u = (const unsigned int*)h1h;
      float a0v = 0.f, a0d = 0.f, a1v = 0.f, a1d = 0.f;
      bool dual = (tid < 256);
#pragma unroll 4
      for (int i = 0; i < 16; ++i) {
        unsigned int hv0 = h0u[16 * s + i];
        unsigned int hv1 = h1u[16 * s + i];
        const unsigned int* w0r = whh0T + (size_t)(16 * s + i) * 768;
        const unsigned int* w1r = whh1T + (size_t)(16 * s + i) * 768;
        a0v = dot2f(h2(w0r[tid]), h2(hv0), a0v);
        a1v = dot2f(h2(w1r[tid]), h2(hv1), a1v);
        if (dual) {
          a0d = dot2f(h2(w0r[512 + tid]), h2(hv0), a0d);
          a1d = dot2f(h2(w1r[512 + tid]), h2(hv1), a1d);
        }
      }
      float* v0 = vec0 + (vbase + s) * 1536 + 768;
      float* v1 = vec1 + (vbase + s) * 1536 + 768;
      astore(v0 + tid, a0v);
      astore(v1 + tid, a1v);
      if (dual) { astore(v0 + 512 + tid, a0d); astore(v1 + 512 + tid, a1d); }
    }
    bar_wait(bar + 0, tgt);        // E1 wait
    // -- softmax (replicated)
    {
      float sum = 0.f;
#pragma unroll
      for (int sp = 0; sp < 8; ++sp) sum += aload(spart + ((size_t)(b * 8 + sp)) * 512 + tid);
      float v = (tid < Lt) ? sum : -3.0e38f;
      float m = v;
#pragma unroll
      for (int off = 32; off; off >>= 1) m = fmaxf(m, __shfl_xor(m, off, 64));
      if ((tid & 63) == 0) red[tid >> 6] = m;
      __syncthreads();
      float M = red[0];
#pragma unroll
      for (int i = 1; i < 8; ++i) M = fmaxf(M, red[i]);
      float e = (tid < Lt) ? __expf(v - M) : 0.f;
      float zz = e;
#pragma unroll
      for (int off = 32; off; off >>= 1) zz += __shfl_xor(zz, off, 64);
      if ((tid & 63) == 0) red[8 + (tid >> 6)] = zz;
      __syncthreads();
      float Z = red[8];
#pragma unroll
      for (int i = 1; i < 8; ++i) Z += red[8 + i];
      att[tid] = __fdividef(e, Z);     // exact 0 for invalid slots
    }
    __syncthreads();
    // -- ctx slice from private kv (h' = 2hh,2hh+1 local)
    {
      int c = tid >> 4, hh = tid & 15;
      float aA = 0.f, aB = 0.f;
#pragma unroll
      for (int j = 0; j < 16; ++j) {
        int l = 16 * c + j;
        half2v kv2 = h2(kv_u[l * 19 + hh]);
        float av = att[l];
        aA = fmaf((float)kv2[0], av, aA);
        aB = fmaf((float)kv2[1], av, aB);
      }
      scr2[c * 35 + 2 * hh] = aA;
      scr2[c * 35 + 2 * hh + 1] = aB;
    }
    __syncthreads();
    if (tid < 32) {
      float a = 0.f;
#pragma unroll
      for (int c = 0; c < 32; ++c) a += scr2[c * 35 + tid];
      xinh[tid] = (_Float16)a;             // ctx local slice = gi0's k-slice
    }
    __syncthreads();
    // -- gi0 k-sliced partials (wih0T: k2 0..127 ctx, 128..255 emb)
    {
      const unsigned int* xu = (const unsigned int*)xinh;   // [0..16) ctx, [16..32) emb pairs
      float g1 = 0.f, g2 = 0.f;
      bool dual = (tid < 256);
#pragma unroll 4
      for (int i = 0; i < 16; ++i) {
        unsigned int xc = xu[i], xe = xu[16 + i];
        const unsigned int* wc = wih0T + (size_t)(16 * s + i) * 768;
        const unsigned int* we = wih0T + (size_t)(128 + 16 * s + i) * 768;
        g1 = dot2f(h2(wc[tid]), h2(xc), g1);
        g1 = dot2f(h2(we[tid]), h2(xe), g1);
        if (dual) {
          g2 = dot2f(h2(wc[512 + tid]), h2(xc), g2);
          g2 = dot2f(h2(we[512 + tid]), h2(xe), g2);
        }
      }
      float* vb = vec0 + (vbase + s) * 1536;
      astore(vb + tid, g1);
      if (dual) astore(vb + 512 + tid, g2);
    }
    bar_arrive(bar + 1);           // E2 arrive: GRU0 gi partials (gh already stored)
    // == B-gap: attn_out slice write (HBM latency hidden) ==
    if ((tid >> 6) == s) attn_out[((size_t)(b * NT + t)) * NL2 + tid] = att[tid];
    bar_wait(bar + 1, tgt);        // E2 wait
    // -- combine0 (replicated sums) + h0 gates
    {
      float t0 = 0.f;
#pragma unroll
      for (int sp = 0; sp < 8; ++sp) {
        const float* vb = vec0 + (vbase + sp) * 1536;
        t0 += aload(vb + tid) + aload(vb + 768 + tid);
      }
      gsum[tid] = t0;
      if (tid < 256) {
        float ti = 0.f;
#pragma unroll
        for (int sp = 0; sp < 8; ++sp) ti += aload(vec0 + (vbase + sp) * 1536 + 512 + tid);
        gsum[512 + tid] = ti;
      } else {
        int j = tid - 256;
        float th = 0.f;
#pragma unroll
        for (int sp = 0; sp < 8; ++sp) th += aload(vec0 + (vbase + sp) * 1536 + 1280 + j);
        gsum[768 + j] = th;
      }
    }
    __syncthreads();
    if (tid < 256) {
      float rr = fast_sigmoid(gsum[tid] + bih0[tid] + bhh0[tid]);
      float zz = fast_sigmoid(gsum[256 + tid] + bih0[256 + tid] + bhh0[256 + tid]);
      float nn = fast_tanh(gsum[512 + tid] + bih0[512 + tid] + rr * (gsum[768 + tid] + bhh0[512 + tid]));
      float hv = (1.f - zz) * nn + zz * h0s[tid];
      h0s[tid] = hv; h0h[tid] = (_Float16)hv;
    }
    __syncthreads();
    // -- gi1 k-sliced partials (wih1 @ h0_new)
    {
      const unsigned int* h0u = (const unsigned int*)h0h;
      float g1 = 0.f, g2 = 0.f;
      bool dual = (tid < 256);
#pragma unroll 4
      for (int i = 0; i < 16; ++i) {
        unsigned int xv = h0u[16 * s + i];
        const unsigned int* wi = wih1T + (size_t)(16 * s + i) * 768;
        g1 = dot2f(h2(wi[tid]), h2(xv), g1);
        if (dual) g2 = dot2f(h2(wi[512 + tid]), h2(xv), g2);
      }
      float* vb = vec1 + (vbase + s) * 1536;
      astore(vb + tid, g1);
      if (dual) astore(vb + 512 + tid, g2);
    }
    bar_arrive(bar + 2);           // E3 arrive: GRU1 gi partials
    // == C-gap: prefetch next-step emb slice into xinh[32..64) (gi0 consumed it) ==
    if (t < NT - 1 && tid >= 480) {
      int j = tid - 480;
      int tok = x[b * NT + t + 1];
      xinh[32 + j] = (_Float16)emb[(size_t)tok * 256 + 32 * s + j];
    }
    bar_wait(bar + 2, tgt);        // E3 wait
    // -- combine1 (replicated) + h1 gates + outs slice
    {
      float t0 = 0.f;
#pragma unroll
      for (int sp = 0; sp < 8; ++sp) {
        const float* vb = vec1 + (vbase + sp) * 1536;
        t0 += aload(vb + tid) + aload(vb + 768 + tid);
      }
      gsum[tid] = t0;
      if (tid < 256) {
        float ti = 0.f;
#pragma unroll
        for (int sp = 0; sp < 8; ++sp) ti += aload(vec1 + (vbase + sp) * 1536 + 512 + tid);
        gsum[512 + tid] = ti;
      } else {
        int j = tid - 256;
        float th = 0.f;
#pragma unroll
        for (int sp = 0; sp < 8; ++sp) th += aload(vec1 + (vbase + sp) * 1536 + 1280 + j);
        gsum[768 + j] = th;
      }
    }
    __syncthreads();
    if (tid < 256) {
      float rr = fast_sigmoid(gsum[tid] + bih1[tid] + bhh1[tid]);
      float zz = fast_sigmoid(gsum[256 + tid] + bih1[256 + tid] + bhh1[256 + tid]);
      float nn = fast_tanh(gsum[512 + tid] + bih1[512 + tid] + rr * (gsum[768 + tid] + bhh1[512 + tid]));
      float hv = (1.f - zz) * nn + zz * h1s[tid];
      h1s[tid] = hv; h1h[tid] = (_Float16)hv;
      if ((tid >> 5) == s) outs_bf[((size_t)(b * NT + t)) * NH + tid] = f2bf(hv);
    }
    __syncthreads();
    // -- appends (all local to this WG's LDS slices)
    if (t < NT - 1) {
      int pos = NTP1 + t;
      if (tid < 16) {
        unsigned short lo = __builtin_bit_cast(unsigned short, h1h[32 * s + 2 * tid]);
        unsigned short hi = __builtin_bit_cast(unsigned short, h1h[32 * s + 2 * tid + 1]);
        kv_u[pos * 19 + tid] = (unsigned int)lo | ((unsigned int)hi << 16);
      }
      {
        int row = tid & 31, ch = tid >> 5;
        scr[ch * 33 + row] = dot16h(wk16 + (size_t)(32 * s + row) * 256 + ch * 16, h1h + ch * 16);
      }
      __syncthreads();
      if (tid < 32) {
        float a = 0.f;
#pragma unroll
        for (int c = 0; c < 16; ++c) a += scr[c * 33 + tid];
        ((_Float16*)kp_u)[pos * 34 + tid] = (_Float16)a;
      }
      __syncthreads();
    }
  }
}

// ---------------- logits GEMM: C(8192x32000) = A(8192x256) * B^T + bias, bf16 MFMA ----------------

__global__ __launch_bounds__(256) void logits_gemm(const unsigned short* __restrict__ A,
                                                   const unsigned short* __restrict__ Bw,
                                                   const float* __restrict__ bias,
                                                   float* __restrict__ C) {
  __shared__ unsigned short As[128][88];
  __shared__ unsigned short Bs[128][88];
  int tid = threadIdx.x;
  int nt = blockIdx.x % 250, mt = blockIdx.x / 250;
  int m0 = mt * 128, n0 = nt * 128;
  int lane = tid & 63, w = tid >> 6;
  int wm = w & 1, wn = w >> 1;
  f32x4 acc[4][4];
#pragma unroll
  for (int m = 0; m < 4; ++m)
#pragma unroll
    for (int n = 0; n < 4; ++n) acc[m][n] = (f32x4)0.0f;

  int r0 = tid >> 3;
  int c0 = (tid & 7) * 8;
  for (int kt = 0; kt < 4; ++kt) {
    __syncthreads();
#pragma unroll
    for (int it = 0; it < 4; ++it) {
      int row = it * 32 + r0;
      u32x4 va = *(const u32x4*)(A + (size_t)(m0 + row) * 256 + kt * 64 + c0);
      u32x4 vb = *(const u32x4*)(Bw + (size_t)(n0 + row) * 256 + kt * 64 + c0);
      *(u32x4*)(&As[row][c0]) = va;
      *(u32x4*)(&Bs[row][c0]) = vb;
    }
    __syncthreads();
#pragma unroll
    for (int ks = 0; ks < 2; ++ks) {
      s16x8 af[4], bf[4];
#pragma unroll
      for (int m = 0; m < 4; ++m)
        af[m] = *(const s16x8*)(&As[wm * 64 + m * 16 + (lane & 15)][ks * 32 + (lane >> 4) * 8]);
#pragma unroll
      for (int n = 0; n < 4; ++n)
        bf[n] = *(const s16x8*)(&Bs[wn * 64 + n * 16 + (lane & 15)][ks * 32 + (lane >> 4) * 8]);
#pragma unroll
      for (int m = 0; m < 4; ++m)
#pragma unroll
        for (int n = 0; n < 4; ++n)
          acc[m][n] = __builtin_amdgcn_mfma_f32_16x16x32_bf16(af[m], bf[n], acc[m][n], 0, 0, 0);
    }
  }
#pragma unroll
  for (int n = 0; n < 4; ++n) {
    int col = n0 + wn * 64 + n * 16 + (lane & 15);
    float bv = bias[col];
#pragma unroll
    for (int m = 0; m < 4; ++m) {
      int rowb = m0 + wm * 64 + m * 16 + (lane >> 4) * 4;
#pragma unroll
      for (int r = 0; r < 4; ++r)
        C[(size_t)(rowb + r) * NV + col] = acc[m][n][r] + bv;
    }
  }
}

// ---------------- host launch ----------------

extern "C" void kernel_launch(void* const* d_in, const int* in_sizes, int n_in,
                              void* d_out, int out_size, void* d_ws, size_t ws_size,
                              hipStream_t stream) {
  const int*   x    = (const int*)d_in[0];
  const float* enc  = (const float*)d_in[1];
  const float* efs  = (const float*)d_in[2];
  const float* emb  = (const float*)d_in[3];
  const float* epw  = (const float*)d_in[4];
  const float* epb  = (const float*)d_in[5];
  const float* wq   = (const float*)d_in[6];
  const float* wk   = (const float*)d_in[7];
  const float* wv   = (const float*)d_in[8];
  const float* wih0 = (const float*)d_in[9];
  const float* whh0 = (const float*)d_in[10];
  const float* bih0 = (const float*)d_in[11];
  const float* bhh0 = (const float*)d_in[12];
  const float* wih1 = (const float*)d_in[13];
  const float* whh1 = (const float*)d_in[14];
  const float* bih1 = (const float*)d_in[15];
  const float* bhh1 = (const float*)d_in[16];
  const float* dw   = (const float*)d_in[17];
  const float* db   = (const float*)d_in[18];

  // workspace layout (bytes). The 16.38MB dwbf16 region is aliased during setup/scan by:
  //   wq16, wk16, wih0T, whh0T, wih1T, whh1T, kvL — all dead before conv_bf16 runs.
  const size_t o_alias  = 0;                            // 16,384,000
  const size_t a_wq16   = 0;                            // 131,072
  const size_t a_wk16   = a_wq16 + 131072;              // 131,072
  const size_t a_wih0T  = a_wk16 + 131072;              // 786,432
  const size_t a_whh0T  = a_wih0T + 786432;             // 393,216
  const size_t a_wih1T  = a_whh0T + 393216;             // 393,216
  const size_t a_whh1T  = a_wih1T + 393216;             // 393,216
  const size_t a_kvL    = a_whh1T + 393216;             // 8,388,608  (ends at 10,616,832)
  const size_t o_wT     = o_alias + 16384000;           // 524,288
  const size_t o_kprojL = o_wT + 524288;                // 8,388,608
  const size_t o_outs   = o_kprojL + 8388608;           // 4,194,304
  const size_t o_spart  = o_outs + 4194304;             // 524,288
  const size_t o_vec0   = o_spart + 524288;             // 3,145,728 (2 bufs x 32 x 8 x 1536 f32)
  const size_t o_vec1   = o_vec0 + 3145728;             // 3,145,728
  const size_t o_bar    = o_vec1 + 3145728;             // 4,096
  const size_t need     = o_bar + 4096;                 // ~36.3 MB
  if (ws_size < need) return;  // fail visibly rather than corrupt

  char* ws = (char*)d_ws;
  unsigned short* dwbf16 = (unsigned short*)(ws + o_alias);
  _Float16* wq16     = (_Float16*)(ws + a_wq16);
  _Float16* wk16     = (_Float16*)(ws + a_wk16);
  unsigned int* wih0T = (unsigned int*)(ws + a_wih0T);
  unsigned int* whh0T = (unsigned int*)(ws + a_whh0T);
  unsigned int* wih1T = (unsigned int*)(ws + a_wih1T);
  unsigned int* whh1T = (unsigned int*)(ws + a_whh1T);
  _Float16* kvL      = (_Float16*)(ws + a_kvL);
  float* wT          = (float*)(ws + o_wT);
  _Float16* kprojL   = (_Float16*)(ws + o_kprojL);
  unsigned short* outs_bf = (unsigned short*)(ws + o_outs);
  float* spart       = (float*)(ws + o_spart);
  float* vec0        = (float*)(ws + o_vec0);
  float* vec1        = (float*)(ws + o_vec1);
  int* bars          = (int*)(ws + o_bar);

  float* logits = (float*)d_out;
  float* attn_out = logits + (size_t)NB * NT * NV;

  hipMemsetAsync(ws + o_bar, 0, 4096, stream);

  // weight prep
  conv_f16_kernel<<<(65536 + 255) / 256, 256, 0, stream>>>(wq, wq16, 65536);
  conv_f16_kernel<<<(65536 + 255) / 256, 256, 0, stream>>>(wk, wk16, 65536);
  packT_kernel<<<(768 * 256 + 255) / 256, 256, 0, stream>>>(wih0, wih0T, 768, 512);
  packT_kernel<<<(768 * 128 + 255) / 256, 256, 0, stream>>>(whh0, whh0T, 768, 256);
  packT_kernel<<<(768 * 128 + 255) / 256, 256, 0, stream>>>(wih1, wih1T, 768, 256);
  packT_kernel<<<(768 * 128 + 255) / 256, 256, 0, stream>>>(whh1, whh1T, 768, 256);
  transpose_kernel<<<(131072 + 255) / 256, 256, 0, stream>>>(epw, wT);

  // encoder projection -> kvL[b][l][h] (f16), then key projections -> kprojL[b][l][g] (f16)
  proj_kernel<<<(NTP1 * NB * 64) / 256, 256, 0, stream>>>(enc, wT, epb, kvL);
  kproj0_kernel<<<NB * 8, 256, 0, stream>>>(kvL, wk, kprojL);

  // cooperative scan: 256 WGs (8 per batch), 512 threads each — 1 WG/CU co-resident
  scan_kernel<<<256, 512, 0, stream>>>(x, efs, emb, wv, bih0, bhh0, bih1, bhh1,
                                       wq16, wk16, wih0T, whh0T, wih1T, whh1T,
                                       (const unsigned int*)kvL, (const unsigned int*)kprojL,
                                       spart, vec0, vec1, bars,
                                       outs_bf, attn_out);

  // now safe to overwrite the alias region with bf16 dense_w
  conv_bf16_kernel<<<(8192000 + 255) / 256, 256, 0, stream>>>(dw, dwbf16, 8192000);

  // final big GEMM: logits
  logits_gemm<<<(NB * NT / 128) * (NV / 128), 256, 0, stream>>>(outs_bf, dwbf16, db, logits);
}